// Round 5
// baseline (162.592 us; speedup 1.0000x reference)
//
#include <hip/hip_runtime.h>

// Problem constants (from reference): B=16, C=1, H=1024, W=1024, fp32.
#define HH 1024
#define WW 1024
#define W4 (WW / 4)
#define ROWS 8           // rows per block; grid = (HH/ROWS, B)

__device__ __forceinline__ float4 fmax4(float4 a, float4 b) {
    return make_float4(fmaxf(a.x, b.x), fmaxf(a.y, b.y),
                       fmaxf(a.z, b.z), fmaxf(a.w, b.w));
}

__device__ __forceinline__ float loss_elem(float x, float t, float dil) {
    // weight: target>0.5 -> 20, elif dilated>0.5 -> 5, else 1
    float w = (t > 0.5f) ? 20.0f : ((dil > 0.5f) ? 5.0f : 1.0f);
    // BCE with logits: max(x,0) - x*t + log1p(exp(-|x|))
    // softplus(-|x|) via HW v_exp_f32 / v_log_f32 (absmax 0.0 since R2).
    float a  = fabsf(x);
    float sp = __logf(1.0f + __expf(-a));
    return w * (fmaxf(x, 0.0f) - x * t + sp);
}

__global__ __launch_bounds__(256) void dilatedweightBCE_main(
        const float* __restrict__ pred,
        const float* __restrict__ target,
        float* __restrict__ partial) {
    // One block per (image b, 8-row band): 256 threads x float4 = 1024 cols.
    // Rolling registers: each target row loaded once per block (band edges
    // re-read by the neighbor block hit L2). Dilation register-only:
    // vertical max in regs, horizontal halo via intra-wave shfl + 2
    // boundary-lane patch loads per wave (L1/L2 hits). NO barriers in the
    // row loop; one shuffle-reduction per block -> tail cost amortized 8x.
    __shared__ float swave[4];

    const int tid  = threadIdx.x;
    const int lane = tid & 63;
    const int c    = tid * 4;                // first column of this thread
    const int b    = blockIdx.y;
    const int h0   = blockIdx.x * ROWS;

    const float* timg = target + (size_t)b * HH * WW;
    const float4* tg  = (const float4*)timg;
    const float4* pg  = (const float4*)(pred + (size_t)b * HH * WW);

    const float4 zero = make_float4(0.0f, 0.0f, 0.0f, 0.0f);
    float4 t_prev = (h0 > 0) ? tg[(size_t)(h0 - 1) * W4 + tid] : zero;
    float4 t_cur  = tg[(size_t)h0 * W4 + tid];

    float s = 0.0f;
    #pragma unroll
    for (int r = 0; r < ROWS; ++r) {
        const int h = h0 + r;
        const bool has_up = (h > 0);
        const bool has_dn = (h < HH - 1);
        const size_t rowoff = (size_t)h * WW;

        float4 t_next = has_dn ? tg[(size_t)(h + 1) * W4 + tid] : zero;
        float4 x      = pg[(size_t)h * W4 + tid];

        float4 vm = fmax4(fmax4(t_prev, t_cur), t_next);

        // horizontal halo: left = vmax at col c-1, right = vmax at col c+4
        float l  = __shfl_up(vm.w, 1);
        float rr = __shfl_down(vm.x, 1);

        if (lane == 0) {             // patch left halo (1 lane/wave)
            l = 0.0f;
            if (c > 0) {
                float v = timg[rowoff + c - 1];
                if (has_up) v = fmaxf(v, timg[rowoff - WW + c - 1]);
                if (has_dn) v = fmaxf(v, timg[rowoff + WW + c - 1]);
                l = v;
            }
        }
        if (lane == 63) {            // patch right halo (1 lane/wave)
            rr = 0.0f;
            if (c + 4 < WW) {
                float v = timg[rowoff + c + 4];
                if (has_up) v = fmaxf(v, timg[rowoff - WW + c + 4]);
                if (has_dn) v = fmaxf(v, timg[rowoff + WW + c + 4]);
                rr = v;
            }
        }

        float d0 = fmaxf(l,    fmaxf(vm.x, vm.y));
        float d1 = fmaxf(vm.x, fmaxf(vm.y, vm.z));
        float d2 = fmaxf(vm.y, fmaxf(vm.z, vm.w));
        float d3 = fmaxf(vm.z, fmaxf(vm.w, rr));

        s += loss_elem(x.x, t_cur.x, d0);
        s += loss_elem(x.y, t_cur.y, d1);
        s += loss_elem(x.z, t_cur.z, d2);
        s += loss_elem(x.w, t_cur.w, d3);

        t_prev = t_cur;
        t_cur  = t_next;
    }

    // wave (64-lane) shuffle reduction, then cross-wave via LDS
    #pragma unroll
    for (int off = 32; off > 0; off >>= 1)
        s += __shfl_down(s, off);

    const int wave = tid >> 6;
    if (lane == 0) swave[wave] = s;
    __syncthreads();
    if (tid == 0) {
        // one plain store per block into a disjoint slot -- zero contention
        partial[blockIdx.y * gridDim.x + blockIdx.x] =
            swave[0] + swave[1] + swave[2] + swave[3];
    }
}

__global__ __launch_bounds__(256) void dilatedweightBCE_reduce(
        const float* __restrict__ partial,
        float* __restrict__ out,
        int npart4,            // number of float4 chunks
        float inv_n) {
    __shared__ float swave[4];
    const int tid = threadIdx.x;

    float s = 0.0f;
    const float4* p4 = (const float4*)partial;
    for (int i = tid; i < npart4; i += 256) {
        float4 v = p4[i];
        s += v.x + v.y + v.z + v.w;
    }

    #pragma unroll
    for (int off = 32; off > 0; off >>= 1)
        s += __shfl_down(s, off);

    const int wave = tid >> 6;
    const int lane = tid & 63;
    if (lane == 0) swave[wave] = s;
    __syncthreads();
    if (tid == 0)
        out[0] = (swave[0] + swave[1] + swave[2] + swave[3]) * inv_n;
}

extern "C" void kernel_launch(void* const* d_in, const int* in_sizes, int n_in,
                              void* d_out, int out_size, void* d_ws, size_t ws_size,
                              hipStream_t stream) {
    const float* pred   = (const float*)d_in[0];
    const float* target = (const float*)d_in[1];
    float* out     = (float*)d_out;
    float* partial = (float*)d_ws;           // 2048 floats = 8 KB scratch

    const int n  = in_sizes[0];              // B*C*H*W
    const int Bn = n / (HH * WW);            // batch (16)
    const int nblocks = (HH / ROWS) * Bn;    // 2048

    dim3 grid(HH / ROWS, Bn);
    dilatedweightBCE_main<<<grid, 256, 0, stream>>>(pred, target, partial);
    dilatedweightBCE_reduce<<<1, 256, 0, stream>>>(partial, out,
                                                   nblocks / 4, 1.0f / (float)n);
}

// Round 6
// 142.116 us; speedup vs baseline: 1.1441x; 1.1441x over previous
//
#include <hip/hip_runtime.h>

// Problem constants (from reference): B=16, C=1, H=1024, W=1024, fp32.
#define HH 1024
#define WW 1024
#define W4 (WW / 4)
#define ROWS 4           // rows per block; grid = (HH/ROWS, B)

__device__ __forceinline__ float fmax3(float a, float b, float c) {
    return fmaxf(a, fmaxf(b, c));
}

__device__ __forceinline__ float loss_elem(float x, float t, float dil) {
    // weight: target>0.5 -> 20, elif dilated>0.5 -> 5, else 1
    float w = (t > 0.5f) ? 20.0f : ((dil > 0.5f) ? 5.0f : 1.0f);
    // BCE with logits: max(x,0) - x*t + log1p(exp(-|x|))
    // softplus via HW v_exp_f32 / v_log_f32 (absmax 0.0 since R2).
    float a  = fabsf(x);
    float sp = __logf(1.0f + __expf(-a));
    return w * (fmaxf(x, 0.0f) - x * t + sp);
}

__global__ __launch_bounds__(256) void dilatedweightBCE_main(
        const float* __restrict__ pred,
        const float* __restrict__ target,
        float* __restrict__ partial) {
    // One block per (image b, 4-row band): 256 threads x float4 = 1024 cols.
    // ALL global loads issued up front (6 target rows + 4 pred rows per
    // thread, fully independent -> max memory-level parallelism; R4/R5 were
    // latency-bound with only 2-4 loads in flight). Halo columns for the 2
    // wave-boundary lanes also hoisted out of the row loop. No barriers
    // until one reduction tail per block (amortized 4x vs R4).
    __shared__ float swave[4];

    const int tid  = threadIdx.x;
    const int lane = tid & 63;
    const int c    = tid * 4;                // first column of this thread
    const int b    = blockIdx.y;
    const int h0   = blockIdx.x * ROWS;

    const float* timg = target + (size_t)b * HH * WW;
    const float4* tg  = (const float4*)timg;
    const float4* pg  = (const float4*)(pred + (size_t)b * HH * WW);
    const float4 zero = make_float4(0.0f, 0.0f, 0.0f, 0.0f);

    // ---- up-front independent loads ----
    float4 tr[ROWS + 2];                     // target rows h0-1 .. h0+ROWS
    tr[0] = (h0 > 0) ? tg[(size_t)(h0 - 1) * W4 + tid] : zero;
    #pragma unroll
    for (int r = 0; r < ROWS; ++r)
        tr[r + 1] = tg[(size_t)(h0 + r) * W4 + tid];
    tr[ROWS + 1] = (h0 + ROWS < HH) ? tg[(size_t)(h0 + ROWS) * W4 + tid] : zero;

    float4 xr[ROWS];                         // pred rows h0 .. h0+ROWS-1
    #pragma unroll
    for (int r = 0; r < ROWS; ++r)
        xr[r] = pg[(size_t)(h0 + r) * W4 + tid];

    // halo columns for wave-boundary lanes (c-1 for lane 0, c+4 for lane 63),
    // vertical max per row, loaded up front so they're off the critical path
    float halo[ROWS];
    #pragma unroll
    for (int r = 0; r < ROWS; ++r) halo[r] = 0.0f;
    if (lane == 0 || lane == 63) {
        const int pc = (lane == 0) ? c - 1 : c + 4;
        if (pc >= 0 && pc < WW) {
            float pv[ROWS + 2];
            pv[0] = (h0 > 0) ? timg[(size_t)(h0 - 1) * WW + pc] : 0.0f;
            #pragma unroll
            for (int r = 0; r < ROWS; ++r)
                pv[r + 1] = timg[(size_t)(h0 + r) * WW + pc];
            pv[ROWS + 1] = (h0 + ROWS < HH)
                         ? timg[(size_t)(h0 + ROWS) * WW + pc] : 0.0f;
            #pragma unroll
            for (int r = 0; r < ROWS; ++r)
                halo[r] = fmax3(pv[r], pv[r + 1], pv[r + 2]);
        }
    }

    // ---- compute ----
    float s = 0.0f;
    #pragma unroll
    for (int r = 0; r < ROWS; ++r) {
        float4 a = tr[r], m = tr[r + 1], d = tr[r + 2];
        float4 vm = make_float4(fmax3(a.x, m.x, d.x), fmax3(a.y, m.y, d.y),
                                fmax3(a.z, m.z, d.z), fmax3(a.w, m.w, d.w));

        float l  = __shfl_up(vm.w, 1);
        float rr = __shfl_down(vm.x, 1);
        if (lane == 0)  l  = halo[r];
        if (lane == 63) rr = halo[r];

        float d0 = fmax3(l,    vm.x, vm.y);
        float d1 = fmax3(vm.x, vm.y, vm.z);
        float d2 = fmax3(vm.y, vm.z, vm.w);
        float d3 = fmax3(vm.z, vm.w, rr);

        float4 x = xr[r];
        s += loss_elem(x.x, m.x, d0);
        s += loss_elem(x.y, m.y, d1);
        s += loss_elem(x.z, m.z, d2);
        s += loss_elem(x.w, m.w, d3);
    }

    // wave (64-lane) shuffle reduction, then cross-wave via LDS
    #pragma unroll
    for (int off = 32; off > 0; off >>= 1)
        s += __shfl_down(s, off);

    const int wave = tid >> 6;
    if (lane == 0) swave[wave] = s;
    __syncthreads();
    if (tid == 0) {
        // one plain store per block into a disjoint slot -- zero contention
        partial[blockIdx.y * gridDim.x + blockIdx.x] =
            swave[0] + swave[1] + swave[2] + swave[3];
    }
}

__global__ __launch_bounds__(256) void dilatedweightBCE_reduce(
        const float* __restrict__ partial,
        float* __restrict__ out,
        int npart4,            // number of float4 chunks
        float inv_n) {
    __shared__ float swave[4];
    const int tid = threadIdx.x;

    float s = 0.0f;
    const float4* p4 = (const float4*)partial;
    for (int i = tid; i < npart4; i += 256) {
        float4 v = p4[i];
        s += v.x + v.y + v.z + v.w;
    }

    #pragma unroll
    for (int off = 32; off > 0; off >>= 1)
        s += __shfl_down(s, off);

    const int wave = tid >> 6;
    const int lane = tid & 63;
    if (lane == 0) swave[wave] = s;
    __syncthreads();
    if (tid == 0)
        out[0] = (swave[0] + swave[1] + swave[2] + swave[3]) * inv_n;
}

extern "C" void kernel_launch(void* const* d_in, const int* in_sizes, int n_in,
                              void* d_out, int out_size, void* d_ws, size_t ws_size,
                              hipStream_t stream) {
    const float* pred   = (const float*)d_in[0];
    const float* target = (const float*)d_in[1];
    float* out     = (float*)d_out;
    float* partial = (float*)d_ws;           // 4096 floats = 16 KB scratch

    const int n  = in_sizes[0];              // B*C*H*W
    const int Bn = n / (HH * WW);            // batch (16)
    const int nblocks = (HH / ROWS) * Bn;    // 4096

    dim3 grid(HH / ROWS, Bn);
    dilatedweightBCE_main<<<grid, 256, 0, stream>>>(pred, target, partial);
    dilatedweightBCE_reduce<<<1, 256, 0, stream>>>(partial, out,
                                                   nblocks / 4, 1.0f / (float)n);
}